// Round 6
// baseline (789.143 us; speedup 1.0000x reference)
//
#include <hip/hip_runtime.h>

#define Bn 4
#define Cn 256
#define CQn 64
#define Nn 4096

using f32x4  = __attribute__((ext_vector_type(4))) float;
using half4  = __attribute__((ext_vector_type(4))) _Float16;
using half8  = __attribute__((ext_vector_type(8))) _Float16;

#define MFMA_F16(a, b, c)  __builtin_amdgcn_mfma_f32_16x16x32_f16((a), (b), (c), 0, 0, 0)
// XOR swizzle on byte-in-row: flips bits 4..6 by (row&7). Same involution on both
// write and read sides. Makes 16-lane row-strided ds_read_b128 2-way (free).
#define SWZ(row, byte) ((unsigned)(byte) ^ ((((unsigned)(row)) & 7u) << 4))

// LDS tiles with 128-byte rows (64 f16), swizzled.
__device__ __forceinline__ half8 lds_read8(const _Float16* base, int row, int slot) {
  return *(const half8*)((const char*)base + row * 128 + SWZ(row, slot * 16));
}

// ---------------------------------------------------------------------------
// proj_all: all 5 projections. z = 0:q<-x3, 1:k1<-x1, 2:k2<-x2, 3:v<-x3, 4:vt<-xt.
// (unchanged — measured fine)
// ---------------------------------------------------------------------------
__global__ __launch_bounds__(256) void proj_all(
    const float* __restrict__ x1, const float* __restrict__ x2,
    const float* __restrict__ x3, const float* __restrict__ xt,
    const float* __restrict__ Wq, const float* __restrict__ bq,
    const float* __restrict__ Wk, const float* __restrict__ bk,
    const float* __restrict__ Wk2, const float* __restrict__ bk2,
    const float* __restrict__ Wv, const float* __restrict__ bv,
    const float* __restrict__ Wv2, const float* __restrict__ bv2,
    _Float16* __restrict__ qt, _Float16* __restrict__ k1t, _Float16* __restrict__ k2t,
    _Float16* __restrict__ v, _Float16* __restrict__ vt)
{
  const int p = blockIdx.z;
  const float* x    = (p == 0 || p == 3) ? x3 : (p == 1) ? x1 : (p == 2) ? x2 : xt;
  const float* W    = (p == 0) ? Wq : (p == 1) ? Wk : (p == 2) ? Wk2 : (p == 3) ? Wv : Wv2;
  const float* bias = (p == 0) ? bq : (p == 1) ? bk : (p == 2) ? bk2 : (p == 3) ? bv : bv2;

  const int b = blockIdx.y;
  const int n0 = blockIdx.x * 64;
  const int tid = threadIdx.x;
  const int w = tid >> 6, lane = tid & 63, quad = lane >> 4, l16 = lane & 15;

  __shared__ _Float16 xT[64 * 256];   // [n][c], 512 B rows, swizzled. 32 KB.

  {
    const int nq = (tid & 15) * 4;
#pragma unroll
    for (int it = 0; it < 4; ++it) {
      const int cg = it * 64 + (tid >> 4) * 4;
      f32x4 xv[4];
#pragma unroll
      for (int ci = 0; ci < 4; ++ci)
        xv[ci] = *(const f32x4*)(x + ((size_t)b * Cn + cg + ci) * Nn + n0 + nq);
#pragma unroll
      for (int ni = 0; ni < 4; ++ni) {
        const int row = nq + ni;
        half4 hv;
#pragma unroll
        for (int ci = 0; ci < 4; ++ci) hv[ci] = (_Float16)xv[ci][ni];
        *(half4*)((char*)xT + row * 512 + SWZ(row, cg * 2)) = hv;
      }
    }
  }
  __syncthreads();

  if (p < 3) {
    _Float16* out = (p == 0) ? qt : (p == 1) ? k1t : k2t;
    const int row = w * 16 + l16;
    f32x4 acc[4] = {};
    for (int kst = 0; kst < 8; ++kst) {
      const half8 a = *(const half8*)((const char*)xT + row * 512 +
                                      SWZ(row, (kst * 4 + quad) * 16));
#pragma unroll
      for (int s = 0; s < 4; ++s) {
        const int o = s * 16 + l16;
        const f32x4 w0 = *(const f32x4*)(W + (size_t)o * Cn + kst * 32 + quad * 8);
        const f32x4 w1 = *(const f32x4*)(W + (size_t)o * Cn + kst * 32 + quad * 8 + 4);
        half8 bf;
#pragma unroll
        for (int j = 0; j < 4; ++j) { bf[j] = (_Float16)w0[j]; bf[4 + j] = (_Float16)w1[j]; }
        acc[s] = MFMA_F16(a, bf, acc[s]);
      }
    }
#pragma unroll
    for (int s = 0; s < 4; ++s) {
      const int o = s * 16 + l16;
      const float bb = bias[o];
#pragma unroll
      for (int r = 0; r < 4; ++r) {
        const int n = n0 + w * 16 + quad * 4 + r;
        out[((size_t)b * Nn + n) * CQn + o] = (_Float16)(acc[s][r] + bb);
      }
    }
  } else {
    _Float16* out = (p == 3) ? v : vt;
    f32x4 acc[4][4] = {};
    for (int kst = 0; kst < 8; ++kst) {
      half8 bt[4];
#pragma unroll
      for (int tt = 0; tt < 4; ++tt) {
        const int rowx = tt * 16 + l16;
        bt[tt] = *(const half8*)((const char*)xT + rowx * 512 +
                                 SWZ(rowx, (kst * 4 + quad) * 16));
      }
#pragma unroll
      for (int s = 0; s < 4; ++s) {
        const int o = w * 64 + s * 16 + l16;
        const f32x4 w0 = *(const f32x4*)(W + (size_t)o * Cn + kst * 32 + quad * 8);
        const f32x4 w1 = *(const f32x4*)(W + (size_t)o * Cn + kst * 32 + quad * 8 + 4);
        half8 a;
#pragma unroll
        for (int j = 0; j < 4; ++j) { a[j] = (_Float16)w0[j]; a[4 + j] = (_Float16)w1[j]; }
#pragma unroll
        for (int tt = 0; tt < 4; ++tt) acc[s][tt] = MFMA_F16(a, bt[tt], acc[s][tt]);
      }
    }
#pragma unroll
    for (int s = 0; s < 4; ++s) {
#pragma unroll
      for (int r = 0; r < 4; ++r) {
        const int o = w * 64 + s * 16 + quad * 4 + r;
        const float bb = bias[o];
#pragma unroll
        for (int tt = 0; tt < 4; ++tt) {
          const int n = n0 + tt * 16 + l16;
          out[((size_t)b * Cn + o) * Nn + n] = (_Float16)(acc[s][tt][r] + bb);
        }
      }
    }
  }
}

// ---------------------------------------------------------------------------
// attn_flash v4: 512 blocks (2/CU!), 512 threads (8 waves), 32 rows/block.
// The round-2 structure had zero cross-phase overlap (1 block/CU, 16 waves in
// lockstep behind every barrier). This version restores TLP: LDS 45 KB ->
// 2 blocks co-resident; one block computes while the other drains barriers.
//  - Sweeps 1/2: round-2 staged-K dbuf (proven), 8-wave grid (ntw=w&1, ms=w>>1).
//  - Sweep 3: one barrier/phase. pp triple-buffered (writer (t+1)%3 vs
//    concurrent reader (t-1)%3 disjoint). V direct-from-global, loads issued
//    at phase top and PINNED with sched_barrier(0) (compiler sank them in
//    rounds 1/3/5 -> VGPR 56-64; the pin forces issue-early), consumed after
//    the barrier: latency covered by S-compute + K-commit + barrier.
//  - PV: wave w owns 32 c-rows x all 32 n; pp broadcast now x8 not x16.
// ---------------------------------------------------------------------------
__global__ __launch_bounds__(512, 4) void attn_flash(
    const _Float16* __restrict__ qt, const _Float16* __restrict__ k1t,
    const _Float16* __restrict__ k2t, const _Float16* __restrict__ v,
    const _Float16* __restrict__ vt,
    const float* __restrict__ x3, const float* __restrict__ xt,
    const float* __restrict__ gamma, const float* __restrict__ gamma2,
    float* __restrict__ attn, float* __restrict__ out1, float* __restrict__ out2)
{
  __shared__ _Float16 Kt[2][2][64 * 64];    // 32 KB [buf][tensor], swizzled
  __shared__ _Float16 ppT[3][32 * 64];      // 12 KB, swizzled 128B rows
  __shared__ float red[8][2][16];
  __shared__ float rLs[32];

  const int i = blockIdx.x;
  const int b = (i & 7) >> 1;                   // batch pinned to XCD pair
  const int nt = ((i >> 3) << 1) | (i & 1);     // 0..127
  const int n0 = nt * 32;
  const int tid = threadIdx.x;
  const int w = tid >> 6, lane = tid & 63, quad = lane >> 4, l16 = lane & 15;
  const int ntw = w & 1;     // n-tile (S phases): rows ntw*16..+16
  const int ms  = w >> 1;    // m-sub  (S phases): m rows ms*16..+16

  const _Float16* k1b = k1t + (size_t)b * Nn * CQn;
  const _Float16* k2b = k2t + (size_t)b * Nn * CQn;
  const _Float16* vb  = v   + (size_t)b * Cn * Nn;
  const _Float16* vtb = vt  + (size_t)b * Cn * Nn;
  const float g1 = gamma[0], g2 = gamma2[0];

  // q fragment straight from global (reused all sweeps)
  const _Float16* qrow = qt + ((size_t)b * Nn + n0 + ntw * 16 + l16) * CQn;
  const half8 aq0 = *(const half8*)(qrow + quad * 8);
  const half8 aq1 = *(const half8*)(qrow + 32 + quad * 8);

  // ---- per-thread K staging geometry: 512 threads x 32 B (2 slots) = 16 KB tile
  const int k_te  = tid >> 8;           // tensor
  const int k_row = (tid >> 2) & 63;    // row
  const int k_sl  = (tid & 3) * 2;      // first of 2 slots
  const size_t kstep = (size_t)64 * CQn;
  const _Float16* kSrcBase = (k_te ? k2b : k1b) + (size_t)k_row * CQn + k_sl * 8;
  _Float16* kD0a = (_Float16*)((char*)Kt[0][k_te] + k_row * 128 + SWZ(k_row, k_sl * 16));
  _Float16* kD0b = (_Float16*)((char*)Kt[0][k_te] + k_row * 128 + SWZ(k_row, (k_sl + 1) * 16));
  _Float16* kD1a = (_Float16*)((char*)Kt[1][k_te] + k_row * 128 + SWZ(k_row, k_sl * 16));
  _Float16* kD1b = (_Float16*)((char*)Kt[1][k_te] + k_row * 128 + SWZ(k_row, (k_sl + 1) * 16));
  // stage K tile 0 into buf 0
  *(half8*)kD0a = *(const half8*)(kSrcBase);
  *(half8*)kD0b = *(const half8*)(kSrcBase + 8);
  __syncthreads();

  const int krow = ms * 16 + l16;

  // ================= sweep 1: lg1/lg2 (staged K, 1 barrier/tile) =================
  float l1a[4] = {0.f, 0.f, 0.f, 0.f}, l2a[4] = {0.f, 0.f, 0.f, 0.f};
#pragma unroll 1
  for (int t = 0; t < 64; ++t) {
    const _Float16* ks = kSrcBase + (size_t)((t + 1) & 63) * kstep;
    const half8 kr0 = *(const half8*)(ks);
    const half8 kr1 = *(const half8*)(ks + 8);
    const _Float16* Kc0 = Kt[t & 1][0];
    const _Float16* Kc1 = Kt[t & 1][1];
    const half8 kb0 = lds_read8(Kc0, krow, quad);
    const half8 kb1 = lds_read8(Kc0, krow, 4 + quad);
    const half8 kb2 = lds_read8(Kc1, krow, quad);
    const half8 kb3 = lds_read8(Kc1, krow, 4 + quad);
    f32x4 S1 = {}; S1 = MFMA_F16(aq0, kb0, S1); S1 = MFMA_F16(aq1, kb1, S1);
    f32x4 S2 = {}; S2 = MFMA_F16(aq0, kb2, S2); S2 = MFMA_F16(aq1, kb3, S2);
#pragma unroll
    for (int r = 0; r < 4; ++r) { l1a[r] += __expf(S1[r]); l2a[r] += __expf(S2[r]); }
    if ((t + 1) & 1) { *(half8*)kD1a = kr0; *(half8*)kD1b = kr1; }
    else             { *(half8*)kD0a = kr0; *(half8*)kD0b = kr1; }
    __syncthreads();
  }
#pragma unroll
  for (int r = 0; r < 4; ++r)
#pragma unroll
    for (int off = 1; off < 16; off <<= 1) {
      l1a[r] += __shfl_xor(l1a[r], off);
      l2a[r] += __shfl_xor(l2a[r], off);
    }
  if (l16 == 0)
#pragma unroll
    for (int r = 0; r < 4; ++r) { red[w][0][quad * 4 + r] = l1a[r]; red[w][1][quad * 4 + r] = l2a[r]; }
  __syncthreads();
  float lg1[4], lg2[4];
#pragma unroll
  for (int r = 0; r < 4; ++r) {
    const int nn = quad * 4 + r;
    float s1 = 0.f, s2 = 0.f;
#pragma unroll
    for (int msk = 0; msk < 4; ++msk) { s1 += red[ntw + 2 * msk][0][nn]; s2 += red[ntw + 2 * msk][1][nn]; }
    lg1[r] = __logf(s1); lg2[r] = __logf(s2);
  }
  __syncthreads();   // red reused below

  // ================= sweep 2: L -> rLs (staged K; K(0) already in buf0) ========
  float La[4] = {0.f, 0.f, 0.f, 0.f};
#pragma unroll 1
  for (int t = 0; t < 64; ++t) {
    const _Float16* ks = kSrcBase + (size_t)((t + 1) & 63) * kstep;
    const half8 kr0 = *(const half8*)(ks);
    const half8 kr1 = *(const half8*)(ks + 8);
    const _Float16* Kc0 = Kt[t & 1][0];
    const _Float16* Kc1 = Kt[t & 1][1];
    const half8 kb0 = lds_read8(Kc0, krow, quad);
    const half8 kb1 = lds_read8(Kc0, krow, 4 + quad);
    const half8 kb2 = lds_read8(Kc1, krow, quad);
    const half8 kb3 = lds_read8(Kc1, krow, 4 + quad);
    f32x4 S1 = {}; S1 = MFMA_F16(aq0, kb0, S1); S1 = MFMA_F16(aq1, kb1, S1);
    f32x4 S2 = {}; S2 = MFMA_F16(aq0, kb2, S2); S2 = MFMA_F16(aq1, kb3, S2);
#pragma unroll
    for (int r = 0; r < 4; ++r) {
      const float a1 = __expf(S1[r] - lg1[r]);
      const float a2 = __expf(S2[r] - lg2[r]);
      La[r] += __expf(a1 + a2);
    }
    if ((t + 1) & 1) { *(half8*)kD1a = kr0; *(half8*)kD1b = kr1; }
    else             { *(half8*)kD0a = kr0; *(half8*)kD0b = kr1; }
    __syncthreads();
  }
  // stage K(1) -> buf1 for sweep 3 (buf0 holds K(0) via wrap; buf1's last reader
  // finished before the loop's final barrier). Published by the barriers below.
  {
    const _Float16* ks = kSrcBase + kstep;
    *(half8*)kD1a = *(const half8*)(ks);
    *(half8*)kD1b = *(const half8*)(ks + 8);
  }
#pragma unroll
  for (int r = 0; r < 4; ++r)
#pragma unroll
    for (int off = 1; off < 16; off <<= 1) La[r] += __shfl_xor(La[r], off);
  if (l16 == 0)
#pragma unroll
    for (int r = 0; r < 4; ++r) red[w][0][quad * 4 + r] = La[r];
  __syncthreads();
  if (tid < 32) {
    float s = 0.f;
#pragma unroll
    for (int msk = 0; msk < 4; ++msk) s += red[(tid >> 4) + 2 * msk][0][tid & 15];
    rLs[tid] = 1.0f / s;
  }
  __syncthreads();

  // ================= sweep 3: pp (3-buf, 1 barrier/phase) + PV + attn =========
  // prologue: S(0) from Kt[0] -> ppT[0]
  {
    const _Float16* Kc0 = Kt[0][0];
    const _Float16* Kc1 = Kt[0][1];
    const half8 kb0 = lds_read8(Kc0, krow, quad);
    const half8 kb1 = lds_read8(Kc0, krow, 4 + quad);
    const half8 kb2 = lds_read8(Kc1, krow, quad);
    const half8 kb3 = lds_read8(Kc1, krow, 4 + quad);
    f32x4 S1 = {}; S1 = MFMA_F16(aq0, kb0, S1); S1 = MFMA_F16(aq1, kb1, S1);
    f32x4 S2 = {}; S2 = MFMA_F16(aq0, kb2, S2); S2 = MFMA_F16(aq1, kb3, S2);
#pragma unroll
    for (int r = 0; r < 4; ++r) {
      const float a1 = __expf(S1[r] - lg1[r]);
      const float a2 = __expf(S2[r] - lg2[r]);
      const float ppv = __expf(a1 + a2);
      const int prow = ntw * 16 + quad * 4 + r;
      const int pcol = ms * 16 + l16;
      *(_Float16*)((char*)ppT[0] + prow * 128 + SWZ(prow, pcol * 2)) = (_Float16)ppv;
    }
  }
  __syncthreads();   // ppT[0] visible; also separates prologue Kt[0] read from C(0) write

  // PV: wave w owns c-rows w*32..+32, all 32 n. V frag: lane l16 = c-row.
  const _Float16* vS00 = vb  + (size_t)(w * 32 +      l16) * Nn + quad * 8;
  const _Float16* vS01 = vb  + (size_t)(w * 32 + 16 + l16) * Nn + quad * 8;
  const _Float16* vS10 = vtb + (size_t)(w * 32 +      l16) * Nn + quad * 8;
  const _Float16* vS11 = vtb + (size_t)(w * 32 + 16 + l16) * Nn + quad * 8;

  const int arow = tid >> 4;               // attn-write row 0..31
  const int ac4  = (tid & 15) * 4;         // attn-write col group (0..60)
  const float arl = rLs[arow];
  float* const abase = attn + ((size_t)b * Nn + n0 + arow) * Nn;

  f32x4 acc[2][2][2] = {};   // [cs][nn][te]
#pragma unroll 1
  for (int t = 0; t < 64; ++t) {
    const int m0 = t * 64;
    // ---- A: issue V(t) + K(t+2) loads; PIN so the compiler can't sink them
    half8 vcur[2][2][2];     // [te][cs][kk]
#pragma unroll
    for (int kk = 0; kk < 2; ++kk) {
      vcur[0][0][kk] = *(const half8*)(vS00 + m0 + kk * 32);
      vcur[0][1][kk] = *(const half8*)(vS01 + m0 + kk * 32);
      vcur[1][0][kk] = *(const half8*)(vS10 + m0 + kk * 32);
      vcur[1][1][kk] = *(const half8*)(vS11 + m0 + kk * 32);
    }
    const _Float16* ks = kSrcBase + (size_t)((t + 2) & 63) * kstep;
    const half8 kr0 = *(const half8*)(ks);
    const half8 kr1 = *(const half8*)(ks + 8);
    __builtin_amdgcn_sched_barrier(0);
    // ---- B: S(t+1) from Kt[(t+1)&1] -> ppT[(t+1)%3]
    {
      const _Float16* Kc0 = Kt[(t + 1) & 1][0];
      const _Float16* Kc1 = Kt[(t + 1) & 1][1];
      const half8 kb0 = lds_read8(Kc0, krow, quad);
      const half8 kb1 = lds_read8(Kc0, krow, 4 + quad);
      const half8 kb2 = lds_read8(Kc1, krow, quad);
      const half8 kb3 = lds_read8(Kc1, krow, 4 + quad);
      f32x4 S1 = {}; S1 = MFMA_F16(aq0, kb0, S1); S1 = MFMA_F16(aq1, kb1, S1);
      f32x4 S2 = {}; S2 = MFMA_F16(aq0, kb2, S2); S2 = MFMA_F16(aq1, kb3, S2);
      _Float16* pN = ppT[(t + 1) % 3];
#pragma unroll
      for (int r = 0; r < 4; ++r) {
        const float a1 = __expf(S1[r] - lg1[r]);
        const float a2 = __expf(S2[r] - lg2[r]);
        const float ppv = __expf(a1 + a2);
        const int prow = ntw * 16 + quad * 4 + r;
        const int pcol = ms * 16 + l16;
        *(_Float16*)((char*)pN + prow * 128 + SWZ(prow, pcol * 2)) = (_Float16)ppv;
      }
    }
    // ---- C: commit K(t+2) -> Kt[t&1] (last reader: S(t) in phase t-1, pre-barrier)
    if (t & 1) { *(half8*)kD1a = kr0; *(half8*)kD1b = kr1; }
    else       { *(half8*)kD0a = kr0; *(half8*)kD0b = kr1; }
    // ---- D
    __syncthreads();
    // ---- E: PV(t) from ppT[t%3] x vcur (V latency covered by B+C+barrier)
    const _Float16* pT = ppT[t % 3];
    half8 ppf[2][2];   // [nn][kk]
#pragma unroll
    for (int nn = 0; nn < 2; ++nn)
#pragma unroll
      for (int kk = 0; kk < 2; ++kk)
        ppf[nn][kk] = lds_read8(pT, nn * 16 + l16, kk * 4 + quad);
#pragma unroll
    for (int cs = 0; cs < 2; ++cs)
#pragma unroll
      for (int nn = 0; nn < 2; ++nn)
#pragma unroll
        for (int kk = 0; kk < 2; ++kk) {
          acc[cs][nn][0] = MFMA_F16(vcur[0][cs][kk], ppf[nn][kk], acc[cs][nn][0]);
          acc[cs][nn][1] = MFMA_F16(vcur[1][cs][kk], ppf[nn][kk], acc[cs][nn][1]);
        }
    // ---- F: attn write (tile t, normalized on the fly)
    {
      const half4 h = *(const half4*)((const char*)pT + arow * 128 + SWZ(arow, ac4 * 2));
      f32x4 o;
#pragma unroll
      for (int jj = 0; jj < 4; ++jj) o[jj] = (float)h[jj] * arl;
      *(f32x4*)(abase + m0 + ac4) = o;
    }
  }

  // ---- epilogue: wave w owns out[c = w*32..+32][n0..+32]; per-lane scalar f32
#pragma unroll
  for (int cs = 0; cs < 2; ++cs)
#pragma unroll
    for (int nn = 0; nn < 2; ++nn) {
      const int n = nn * 16 + l16;
      const float rl = rLs[n];
#pragma unroll
      for (int r = 0; r < 4; ++r) {
        const int c = w * 32 + cs * 16 + quad * 4 + r;
        const size_t base = ((size_t)b * Cn + c) * Nn + n0 + n;
        out1[base] = g1 * acc[cs][nn][0][r] * rl + x3[base];
        out2[base] = g2 * acc[cs][nn][1][r] * rl + xt[base];
      }
    }
}

// ---------------------------------------------------------------------------
extern "C" void kernel_launch(void* const* d_in, const int* in_sizes, int n_in,
                              void* d_out, int out_size, void* d_ws, size_t ws_size,
                              hipStream_t stream) {
  const float* x1  = (const float*)d_in[0];
  const float* x2  = (const float*)d_in[1];
  const float* x3  = (const float*)d_in[2];
  const float* xt  = (const float*)d_in[3];
  const float* Wq  = (const float*)d_in[4];
  const float* bq  = (const float*)d_in[5];
  const float* Wk  = (const float*)d_in[6];
  const float* bk  = (const float*)d_in[7];
  const float* Wk2 = (const float*)d_in[8];
  const float* bk2 = (const float*)d_in[9];
  const float* Wv  = (const float*)d_in[10];
  const float* bv  = (const float*)d_in[11];
  const float* Wv2 = (const float*)d_in[12];
  const float* bv2 = (const float*)d_in[13];
  const float* gamma  = (const float*)d_in[14];
  const float* gamma2 = (const float*)d_in[15];

  float* outp = (float*)d_out;
  float* attn = outp;                                   // B*N*N
  float* out1 = outp + (size_t)Bn * Nn * Nn;            // B*C*N
  float* out2 = out1 + (size_t)Bn * Cn * Nn;

  _Float16* qt  = (_Float16*)d_ws;                      // B*N*CQ f16
  _Float16* k1t = qt + (size_t)Bn * Nn * CQn;
  _Float16* k2t = k1t + (size_t)Bn * Nn * CQn;
  _Float16* v   = k2t + (size_t)Bn * Nn * CQn;          // B*C*N f16
  _Float16* vt  = v + (size_t)Bn * Cn * Nn;

  proj_all<<<dim3(Nn / 64, Bn, 5), 256, 0, stream>>>(
      x1, x2, x3, xt, Wq, bq, Wk, bk, Wk2, bk2, Wv, bv, Wv2, bv2,
      qt, k1t, k2t, v, vt);
  attn_flash<<<dim3(Bn * Nn / 32), 512, 0, stream>>>(
      qt, k1t, k2t, v, vt, x3, xt, gamma, gamma2, attn, out1, out2);
}

// Round 7
// 617.704 us; speedup vs baseline: 1.2775x; 1.2775x over previous
//
#include <hip/hip_runtime.h>

#define Bn 4
#define Cn 256
#define CQn 64
#define Nn 4096

using f32x4  = __attribute__((ext_vector_type(4))) float;
using half4  = __attribute__((ext_vector_type(4))) _Float16;
using half8  = __attribute__((ext_vector_type(8))) _Float16;

#define MFMA_F16(a, b, c)  __builtin_amdgcn_mfma_f32_16x16x32_f16((a), (b), (c), 0, 0, 0)
// XOR swizzle on byte-in-row: flips bits 4..6 by (row&7). Same involution on both
// write and read sides. Makes 16-lane row-strided ds_read_b128 2-way (free).
#define SWZ(row, byte) ((unsigned)(byte) ^ ((((unsigned)(row)) & 7u) << 4))

// LDS tiles with 128-byte rows (64 f16), swizzled.
__device__ __forceinline__ half8 lds_read8(const _Float16* base, int row, int slot) {
  return *(const half8*)((const char*)base + row * 128 + SWZ(row, slot * 16));
}

// ---------------------------------------------------------------------------
// proj_all: all 5 projections. z = 0:q<-x3, 1:k1<-x1, 2:k2<-x2, 3:v<-x3, 4:vt<-xt.
// (unchanged — measured fine)
// ---------------------------------------------------------------------------
__global__ __launch_bounds__(256) void proj_all(
    const float* __restrict__ x1, const float* __restrict__ x2,
    const float* __restrict__ x3, const float* __restrict__ xt,
    const float* __restrict__ Wq, const float* __restrict__ bq,
    const float* __restrict__ Wk, const float* __restrict__ bk,
    const float* __restrict__ Wk2, const float* __restrict__ bk2,
    const float* __restrict__ Wv, const float* __restrict__ bv,
    const float* __restrict__ Wv2, const float* __restrict__ bv2,
    _Float16* __restrict__ qt, _Float16* __restrict__ k1t, _Float16* __restrict__ k2t,
    _Float16* __restrict__ v, _Float16* __restrict__ vt)
{
  const int p = blockIdx.z;
  const float* x    = (p == 0 || p == 3) ? x3 : (p == 1) ? x1 : (p == 2) ? x2 : xt;
  const float* W    = (p == 0) ? Wq : (p == 1) ? Wk : (p == 2) ? Wk2 : (p == 3) ? Wv : Wv2;
  const float* bias = (p == 0) ? bq : (p == 1) ? bk : (p == 2) ? bk2 : (p == 3) ? bv : bv2;

  const int b = blockIdx.y;
  const int n0 = blockIdx.x * 64;
  const int tid = threadIdx.x;
  const int w = tid >> 6, lane = tid & 63, quad = lane >> 4, l16 = lane & 15;

  __shared__ _Float16 xT[64 * 256];   // [n][c], 512 B rows, swizzled. 32 KB.

  {
    const int nq = (tid & 15) * 4;
#pragma unroll
    for (int it = 0; it < 4; ++it) {
      const int cg = it * 64 + (tid >> 4) * 4;
      f32x4 xv[4];
#pragma unroll
      for (int ci = 0; ci < 4; ++ci)
        xv[ci] = *(const f32x4*)(x + ((size_t)b * Cn + cg + ci) * Nn + n0 + nq);
#pragma unroll
      for (int ni = 0; ni < 4; ++ni) {
        const int row = nq + ni;
        half4 hv;
#pragma unroll
        for (int ci = 0; ci < 4; ++ci) hv[ci] = (_Float16)xv[ci][ni];
        *(half4*)((char*)xT + row * 512 + SWZ(row, cg * 2)) = hv;
      }
    }
  }
  __syncthreads();

  if (p < 3) {
    _Float16* out = (p == 0) ? qt : (p == 1) ? k1t : k2t;
    const int row = w * 16 + l16;
    f32x4 acc[4] = {};
    for (int kst = 0; kst < 8; ++kst) {
      const half8 a = *(const half8*)((const char*)xT + row * 512 +
                                      SWZ(row, (kst * 4 + quad) * 16));
#pragma unroll
      for (int s = 0; s < 4; ++s) {
        const int o = s * 16 + l16;
        const f32x4 w0 = *(const f32x4*)(W + (size_t)o * Cn + kst * 32 + quad * 8);
        const f32x4 w1 = *(const f32x4*)(W + (size_t)o * Cn + kst * 32 + quad * 8 + 4);
        half8 bf;
#pragma unroll
        for (int j = 0; j < 4; ++j) { bf[j] = (_Float16)w0[j]; bf[4 + j] = (_Float16)w1[j]; }
        acc[s] = MFMA_F16(a, bf, acc[s]);
      }
    }
#pragma unroll
    for (int s = 0; s < 4; ++s) {
      const int o = s * 16 + l16;
      const float bb = bias[o];
#pragma unroll
      for (int r = 0; r < 4; ++r) {
        const int n = n0 + w * 16 + quad * 4 + r;
        out[((size_t)b * Nn + n) * CQn + o] = (_Float16)(acc[s][r] + bb);
      }
    }
  } else {
    _Float16* out = (p == 3) ? v : vt;
    f32x4 acc[4][4] = {};
    for (int kst = 0; kst < 8; ++kst) {
      half8 bt[4];
#pragma unroll
      for (int tt = 0; tt < 4; ++tt) {
        const int rowx = tt * 16 + l16;
        bt[tt] = *(const half8*)((const char*)xT + rowx * 512 +
                                 SWZ(rowx, (kst * 4 + quad) * 16));
      }
#pragma unroll
      for (int s = 0; s < 4; ++s) {
        const int o = w * 64 + s * 16 + l16;
        const f32x4 w0 = *(const f32x4*)(W + (size_t)o * Cn + kst * 32 + quad * 8);
        const f32x4 w1 = *(const f32x4*)(W + (size_t)o * Cn + kst * 32 + quad * 8 + 4);
        half8 a;
#pragma unroll
        for (int j = 0; j < 4; ++j) { a[j] = (_Float16)w0[j]; a[4 + j] = (_Float16)w1[j]; }
#pragma unroll
        for (int tt = 0; tt < 4; ++tt) acc[s][tt] = MFMA_F16(a, bt[tt], acc[s][tt]);
      }
    }
#pragma unroll
    for (int s = 0; s < 4; ++s) {
#pragma unroll
      for (int r = 0; r < 4; ++r) {
        const int o = w * 64 + s * 16 + quad * 4 + r;
        const float bb = bias[o];
#pragma unroll
        for (int tt = 0; tt < 4; ++tt) {
          const int n = n0 + tt * 16 + l16;
          out[((size_t)b * Cn + o) * Nn + n] = (_Float16)(acc[s][tt][r] + bb);
        }
      }
    }
  }
}

// ---------------------------------------------------------------------------
// attn_flash v5 = round-2 kernel (measured 267 µs) + ONE change:
//   ppT double-buffered (8->16 KB) and the attn global store of tile t-1
//   moved to the TOP of phase t. barrier1 now covers the store drain together
//   with the V/K staging-load drain (one vmcnt(0) drain per phase instead of
//   two); barrier2 drains lgkm only. Everything else byte-identical to the
//   267 µs kernel: 256 blocks (1/CU), 1024 thr, 64 rows/block, K dbuf staged,
//   V single-buffer staged (load top / ds_write bottom — the only
//   latency-hiding pattern this compiler respects; rounds 3/5/6 proved
//   reg-prefetch alternatives all sink and regress 1.6-2.1x).
// ---------------------------------------------------------------------------
__global__ __launch_bounds__(1024, 4) void attn_flash(
    const _Float16* __restrict__ qt, const _Float16* __restrict__ k1t,
    const _Float16* __restrict__ k2t, const _Float16* __restrict__ v,
    const _Float16* __restrict__ vt,
    const float* __restrict__ x3, const float* __restrict__ xt,
    const float* __restrict__ gamma, const float* __restrict__ gamma2,
    float* __restrict__ attn, float* __restrict__ out1, float* __restrict__ out2)
{
  __shared__ _Float16 qT[64 * 64];          //  8 KB
  __shared__ _Float16 Kt[2][2][64 * 64];    // 32 KB [buf][tensor]
  __shared__ _Float16 Vt[2][256 * 64];      // 64 KB [tensor]
  __shared__ _Float16 ppT[2][64 * 64];      // 16 KB (dbuf)
  __shared__ float red[16][2][16];
  __shared__ float rLs[64];

  const int i = blockIdx.x;
  const int b = (i & 7) >> 1;                   // batch pinned to XCD pair
  const int nt = ((i >> 3) << 1) | (i & 1);     // 0..63
  const int n0 = nt * 64;
  const int tid = threadIdx.x;
  const int w = tid >> 6, lane = tid & 63, quad = lane >> 4, l16 = lane & 15;
  const int ntw = w & 3;     // n-tile (S phases)
  const int ms  = w >> 2;    // m-sub  (S phases)

  const _Float16* k1b = k1t + (size_t)b * Nn * CQn;
  const _Float16* k2b = k2t + (size_t)b * Nn * CQn;
  const _Float16* vb  = v   + (size_t)b * Cn * Nn;
  const _Float16* vtb = vt  + (size_t)b * Cn * Nn;
  const float g1 = gamma[0], g2 = gamma2[0];

  // ---- stage qT (64 x 64 f16): thread covers 8 B
  {
    const int row = tid >> 4, s8 = tid & 15;
    const half4 qv = *(const half4*)(qt + ((size_t)b * Nn + n0 + row) * CQn + s8 * 4);
    *(half4*)((char*)qT + row * 128 + SWZ(row, s8 * 8)) = qv;
  }

  // ---- per-thread K staging geometry (16 KB tile: thread covers 16 B)
  const int k_te  = tid >> 9;
  const int k_row = (tid >> 3) & 63;
  const int k_sl  = tid & 7;
  const _Float16* kSrcBase = (k_te ? k2b : k1b) + (size_t)k_row * CQn + k_sl * 8;
  _Float16* kDst0 = (_Float16*)((char*)Kt[0][k_te] + k_row * 128 + SWZ(k_row, k_sl * 16));
  _Float16* kDst1 = (_Float16*)((char*)Kt[1][k_te] + k_row * 128 + SWZ(k_row, k_sl * 16));
  // stage K tile 0 into buf 0
  *(half8*)kDst0 = *(const half8*)kSrcBase;
  __syncthreads();

  const half8 aq0 = lds_read8(qT, ntw * 16 + l16, quad);
  const half8 aq1 = lds_read8(qT, ntw * 16 + l16, 4 + quad);
  const int krow = ms * 16 + l16;
  const size_t kstep = (size_t)64 * CQn;

  // ================= sweep 1: lg1/lg2 =================
  float l1a[4] = {0.f, 0.f, 0.f, 0.f}, l2a[4] = {0.f, 0.f, 0.f, 0.f};
#pragma unroll 1
  for (int t = 0; t < 64; ++t) {
    const half8 kreg = *(const half8*)(kSrcBase + (size_t)((t + 1) & 63) * kstep);
    const _Float16* Kc0 = Kt[t & 1][0];
    const _Float16* Kc1 = Kt[t & 1][1];
    const half8 kb0 = lds_read8(Kc0, krow, quad);
    const half8 kb1 = lds_read8(Kc0, krow, 4 + quad);
    const half8 kb2 = lds_read8(Kc1, krow, quad);
    const half8 kb3 = lds_read8(Kc1, krow, 4 + quad);
    f32x4 S1 = {}; S1 = MFMA_F16(aq0, kb0, S1); S1 = MFMA_F16(aq1, kb1, S1);
    f32x4 S2 = {}; S2 = MFMA_F16(aq0, kb2, S2); S2 = MFMA_F16(aq1, kb3, S2);
#pragma unroll
    for (int r = 0; r < 4; ++r) { l1a[r] += __expf(S1[r]); l2a[r] += __expf(S2[r]); }
    *(half8*)(((t + 1) & 1) ? kDst1 : kDst0) = kreg;
    __syncthreads();
  }
#pragma unroll
  for (int r = 0; r < 4; ++r)
#pragma unroll
    for (int off = 1; off < 16; off <<= 1) {
      l1a[r] += __shfl_xor(l1a[r], off);
      l2a[r] += __shfl_xor(l2a[r], off);
    }
  if (l16 == 0)
#pragma unroll
    for (int r = 0; r < 4; ++r) { red[w][0][quad * 4 + r] = l1a[r]; red[w][1][quad * 4 + r] = l2a[r]; }
  __syncthreads();
  float lg1[4], lg2[4];
#pragma unroll
  for (int r = 0; r < 4; ++r) {
    const int nn = quad * 4 + r;
    float s1 = 0.f, s2 = 0.f;
#pragma unroll
    for (int msk = 0; msk < 4; ++msk) { s1 += red[ntw + 4 * msk][0][nn]; s2 += red[ntw + 4 * msk][1][nn]; }
    lg1[r] = __logf(s1); lg2[r] = __logf(s2);
  }
  __syncthreads();

  // ================= sweep 2: L -> rLs =================
  float La[4] = {0.f, 0.f, 0.f, 0.f};
#pragma unroll 1
  for (int t = 0; t < 64; ++t) {
    const half8 kreg = *(const half8*)(kSrcBase + (size_t)((t + 1) & 63) * kstep);
    const _Float16* Kc0 = Kt[t & 1][0];
    const _Float16* Kc1 = Kt[t & 1][1];
    const half8 kb0 = lds_read8(Kc0, krow, quad);
    const half8 kb1 = lds_read8(Kc0, krow, 4 + quad);
    const half8 kb2 = lds_read8(Kc1, krow, quad);
    const half8 kb3 = lds_read8(Kc1, krow, 4 + quad);
    f32x4 S1 = {}; S1 = MFMA_F16(aq0, kb0, S1); S1 = MFMA_F16(aq1, kb1, S1);
    f32x4 S2 = {}; S2 = MFMA_F16(aq0, kb2, S2); S2 = MFMA_F16(aq1, kb3, S2);
#pragma unroll
    for (int r = 0; r < 4; ++r) {
      const float a1 = __expf(S1[r] - lg1[r]);
      const float a2 = __expf(S2[r] - lg2[r]);
      La[r] += __expf(a1 + a2);
    }
    *(half8*)(((t + 1) & 1) ? kDst1 : kDst0) = kreg;
    __syncthreads();
  }
#pragma unroll
  for (int r = 0; r < 4; ++r)
#pragma unroll
    for (int off = 1; off < 16; off <<= 1) La[r] += __shfl_xor(La[r], off);
  if (l16 == 0)
#pragma unroll
    for (int r = 0; r < 4; ++r) red[w][0][quad * 4 + r] = La[r];
  __syncthreads();
  if (tid < 64) {
    float s = 0.f;
#pragma unroll
    for (int msk = 0; msk < 4; ++msk) s += red[(tid >> 4) + 4 * msk][0][tid & 15];
    rLs[tid] = 1.0f / s;
  }
  __syncthreads();

  // ---- per-thread V staging geometry (64 KB tile: thread covers 4 x 16 B)
  const int v_te = tid >> 9;
  const int v_c  = (tid >> 1) & 255;
  const int v_s0 = (tid & 1) * 4;
  const _Float16* vSrcBase = (v_te ? vtb : vb) + (size_t)v_c * Nn + v_s0 * 8;
  char* vDstB = (char*)Vt[v_te] + v_c * 128;

  const int arow = tid >> 4;               // attn-write row 0..63
  const int ac4  = (tid & 15) * 4;         // attn-write col group
  const float arl = rLs[arow];
  float* const abase = attn + ((size_t)b * Nn + n0 + arow) * Nn;

  // ================= sweep 3: pp(dbuf) + PV + deferred attn store =============
  f32x4 acc[4][2] = {};   // [n-tile][tensor]
#pragma unroll 1
  for (int t = 0; t < 64; ++t) {
    const int m0 = t * 64;
    // deferred attn store of tile t-1 (drains at barrier1 with the staging loads)
    if (t) {
      const _Float16* pPrev = ppT[(t - 1) & 1];
      const half4 h = *(const half4*)((const char*)pPrev + arow * 128 + SWZ(arow, ac4 * 2));
      f32x4 o;
#pragma unroll
      for (int jj = 0; jj < 4; ++jj) o[jj] = (float)h[jj] * arl;
      *(f32x4*)(abase + (m0 - 64) + ac4) = o;
    }
    // issue staging loads (committed to LDS at end of phase A)
    half8 vreg[4];
#pragma unroll
    for (int j = 0; j < 4; ++j) vreg[j] = *(const half8*)(vSrcBase + m0 + j * 8);
    const half8 kreg = *(const half8*)(kSrcBase + (size_t)((t + 1) & 63) * kstep);
    // S(t) from K[t]
    const _Float16* Kc0 = Kt[t & 1][0];
    const _Float16* Kc1 = Kt[t & 1][1];
    const half8 kb0 = lds_read8(Kc0, krow, quad);
    const half8 kb1 = lds_read8(Kc0, krow, 4 + quad);
    const half8 kb2 = lds_read8(Kc1, krow, quad);
    const half8 kb3 = lds_read8(Kc1, krow, 4 + quad);
    f32x4 S1 = {}; S1 = MFMA_F16(aq0, kb0, S1); S1 = MFMA_F16(aq1, kb1, S1);
    f32x4 S2 = {}; S2 = MFMA_F16(aq0, kb2, S2); S2 = MFMA_F16(aq1, kb3, S2);
    // pp (unnormalized, f16) -> ppT[t&1]
    _Float16* pCur = ppT[t & 1];
#pragma unroll
    for (int r = 0; r < 4; ++r) {
      const float a1 = __expf(S1[r] - lg1[r]);
      const float a2 = __expf(S2[r] - lg2[r]);
      const float ppv = __expf(a1 + a2);
      const int prow = ntw * 16 + quad * 4 + r;
      const int pcol = ms * 16 + l16;
      *(_Float16*)((char*)pCur + prow * 128 + SWZ(prow, pcol * 2)) = (_Float16)ppv;
    }
    // commit staged tiles
#pragma unroll
    for (int j = 0; j < 4; ++j)
      *(half8*)(vDstB + SWZ(v_c, (v_s0 + j) * 16)) = vreg[j];
    *(half8*)(((t + 1) & 1) ? kDst1 : kDst0) = kreg;
    __syncthreads();                              // barrier1: pp, V[t], K[t+1] ready
    // PV: wave w owns c-rows w*16..+16, all 4 n-tiles
#pragma unroll
    for (int kk = 0; kk < 2; ++kk) {
      const half8 A1 = lds_read8(Vt[0], w * 16 + l16, kk * 4 + quad);
      const half8 A2 = lds_read8(Vt[1], w * 16 + l16, kk * 4 + quad);
#pragma unroll
      for (int nn = 0; nn < 4; ++nn) {
        const half8 pb = lds_read8(pCur, nn * 16 + l16, kk * 4 + quad);
        acc[nn][0] = MFMA_F16(A1, pb, acc[nn][0]);
        acc[nn][1] = MFMA_F16(A2, pb, acc[nn][1]);
      }
    }
    __syncthreads();                              // barrier2: lgkm-only drain (no stores)
  }
  // attn store of the last tile (t=63) from ppT[1]
  {
    const _Float16* pPrev = ppT[1];
    const half4 h = *(const half4*)((const char*)pPrev + arow * 128 + SWZ(arow, ac4 * 2));
    f32x4 o;
#pragma unroll
    for (int jj = 0; jj < 4; ++jj) o[jj] = (float)h[jj] * arl;
    *(f32x4*)(abase + 63 * 64 + ac4) = o;
  }

  // ---- epilogue: each wave owns distinct c-rows; no cross-wave reduce
#pragma unroll
  for (int nn = 0; nn < 4; ++nn) {
    const float rl = rLs[nn * 16 + l16];
#pragma unroll
    for (int r = 0; r < 4; ++r) {
      const int c = w * 16 + quad * 4 + r;
      const size_t base = ((size_t)b * Cn + c) * Nn + n0 + nn * 16 + l16;
      out1[base] = g1 * acc[nn][0][r] * rl + x3[base];
      out2[base] = g2 * acc[nn][1][r] * rl + xt[base];
    }
  }
}

// ---------------------------------------------------------------------------
extern "C" void kernel_launch(void* const* d_in, const int* in_sizes, int n_in,
                              void* d_out, int out_size, void* d_ws, size_t ws_size,
                              hipStream_t stream) {
  const float* x1  = (const float*)d_in[0];
  const float* x2  = (const float*)d_in[1];
  const float* x3  = (const float*)d_in[2];
  const float* xt  = (const float*)d_in[3];
  const float* Wq  = (const float*)d_in[4];
  const float* bq  = (const float*)d_in[5];
  const float* Wk  = (const float*)d_in[6];
  const float* bk  = (const float*)d_in[7];
  const float* Wk2 = (const float*)d_in[8];
  const float* bk2 = (const float*)d_in[9];
  const float* Wv  = (const float*)d_in[10];
  const float* bv  = (const float*)d_in[11];
  const float* Wv2 = (const float*)d_in[12];
  const float* bv2 = (const float*)d_in[13];
  const float* gamma  = (const float*)d_in[14];
  const float* gamma2 = (const float*)d_in[15];

  float* outp = (float*)d_out;
  float* attn = outp;                                   // B*N*N
  float* out1 = outp + (size_t)Bn * Nn * Nn;            // B*C*N
  float* out2 = out1 + (size_t)Bn * Cn * Nn;            // B*C*N

  _Float16* qt  = (_Float16*)d_ws;                      // B*N*CQ f16
  _Float16* k1t = qt + (size_t)Bn * Nn * CQn;
  _Float16* k2t = k1t + (size_t)Bn * Nn * CQn;
  _Float16* v   = k2t + (size_t)Bn * Nn * CQn;          // B*C*N f16
  _Float16* vt  = v + (size_t)Bn * Cn * Nn;

  proj_all<<<dim3(Nn / 64, Bn, 5), 256, 0, stream>>>(
      x1, x2, x3, xt, Wq, bq, Wk, bk, Wk2, bk2, Wv, bv, Wv2, bv2,
      qt, k1t, k2t, v, vt);
  attn_flash<<<dim3(Bn * Nn / 64), 1024, 0, stream>>>(
      qt, k1t, k2t, v, vt, x3, xt, gamma, gamma2, attn, out1, out2);
}